// Round 5
// baseline (404.351 us; speedup 1.0000x reference)
//
#include <hip/hip_runtime.h>

// HMM forward scan, one workgroup per unit u. U=256, N=64, S=4, B=64, T=1024.
// Wave w owns batches [16w,16w+16); lane (q=lane>>4,l=lane&15) owns batch
// b=16w+l and the 16 states j = sig(jt, 4q+r).
//
// sig() row permutation: each lane's MFMA C-layout accumulator values are
// exactly its own next-step B-operand k-slices -> no LDS round-trip.
// E via MFMA (K=4 zero-padded): no Bcol register pressure.
// ss via all-ones MFMA: D[m][b] = sum_k g[k][b] -- every lane gets the full
// 64-state sum for its own batch. Replaces 3 ds_bpermute shuffles whose
// ~120-cyc LDS latency was exposed at 1 wave/SIMD (R4: 814 cyc/step vs
// ~270-cyc MFMA floor). T-loop now has ZERO DS instructions.
//
// Normalization (R4 scheme, verified): Ev_{t+1} packed with rs_{t-1};
// magnitude recurrence z^2-z+1 (unit circle, bounded). Exact ll:
// ll_t = ll_{t-1} + sigma_t - sigma_{t-1} + sigma_{t-2}, sigma=log(ss).

#define U_ 256
#define N_ 64
#define S_ 4
#define B_ 64
#define T_ 1024
#define ROWP 72

typedef __attribute__((ext_vector_type(8))) __bf16 bf16x8;
typedef __attribute__((ext_vector_type(4))) float floatx4;

__device__ __forceinline__ int sig(int jt, int m) {
    return 32 * (jt >> 1) + 4 * (jt & 1) + 8 * (m >> 2) + (m & 3);
}

__launch_bounds__(256, 1)
__global__ void hmm_fwd_kernel(const float* __restrict__ xg,     // [B][T][S]
                               const float* __restrict__ trans,  // [U][N][N]
                               const float* __restrict__ emis,   // [U][N][S]
                               const float* __restrict__ initk,  // [U][N]
                               float* __restrict__ out)          // [B][T][U]
{
    __shared__ __bf16 AT[N_ * ROWP];
    __shared__ float BemS[N_][S_];
    __shared__ float IS[N_];

    const int bid = blockIdx.x;
    const int u = ((bid & 7) << 5) | (bid >> 3);   // XCD-aware u swizzle
    const int tid = threadIdx.x;
    const int lane = tid & 63;
    const int w = tid >> 6;
    const int q = lane >> 4;
    const int l = lane & 15;

    // ---------------- prologue: softmaxes (one-time) ----------------
    if (tid < 64) {
        const float* rowp = trans + (u * N_ + tid) * N_;
        float v[N_];
        #pragma unroll
        for (int k = 0; k < 16; ++k) {
            floatx4 t4 = *(const floatx4*)(rowp + 4 * k);
            v[4*k] = t4.x; v[4*k+1] = t4.y; v[4*k+2] = t4.z; v[4*k+3] = t4.w;
        }
        float m = v[0];
        #pragma unroll
        for (int j = 1; j < N_; ++j) m = fmaxf(m, v[j]);
        float s = 0.f;
        #pragma unroll
        for (int j = 0; j < N_; ++j) { v[j] = __expf(v[j] - m); s += v[j]; }
        float inv = 1.0f / s;
        #pragma unroll
        for (int j = 0; j < N_; ++j) AT[j * ROWP + tid] = (__bf16)(v[j] * inv);
    } else if (tid < 128) {
        int n = tid - 64;
        floatx4 e4 = *(const floatx4*)(emis + (u * N_ + n) * S_);
        float m = fmaxf(fmaxf(e4.x, e4.y), fmaxf(e4.z, e4.w));
        float a = __expf(e4.x - m), b2 = __expf(e4.y - m);
        float c = __expf(e4.z - m), d = __expf(e4.w - m);
        float inv = 1.0f / (a + b2 + c + d);
        BemS[n][0] = a*inv; BemS[n][1] = b2*inv; BemS[n][2] = c*inv; BemS[n][3] = d*inv;
    } else if (tid < 192) {
        int j = tid - 128;
        float v = initk[u * N_ + j];
        float m = v;
        #pragma unroll
        for (int s = 1; s < 64; s <<= 1) m = fmaxf(m, __shfl_xor(m, s, 64));
        float e = __expf(v - m);
        float ssum = e;
        #pragma unroll
        for (int s = 1; s < 64; s <<= 1) ssum += __shfl_xor(ssum, s, 64);
        IS[j] = e / ssum;
    }
    __syncthreads();

    // ------------- persistent register state -------------
    bf16x8 afrag[4][2];
    #pragma unroll
    for (int jt = 0; jt < 4; ++jt)
        #pragma unroll
        for (int kt = 0; kt < 2; ++kt)
            afrag[jt][kt] = *(const bf16x8*)&AT[sig(jt, l) * ROWP + 32*kt + 8*q];

    // Emission A-frag: A_E[m][k] = Bem[sig(jt,m)][k] for k<4 (q==0), else 0.
    bf16x8 afragE[4];
    #pragma unroll
    for (int jt = 0; jt < 4; ++jt) {
        #pragma unroll
        for (int p = 0; p < 8; ++p) afragE[jt][p] = (__bf16)0.f;
        if (q == 0) {
            #pragma unroll
            for (int c = 0; c < 4; ++c)
                afragE[jt][c] = (__bf16)BemS[sig(jt, l)][c];
        }
    }

    // All-ones A-frag for the ss reduce-MFMA: D[m][b] = sum_k B[k][b].
    bf16x8 onesA;
    #pragma unroll
    for (int p = 0; p < 8; ++p) onesA[p] = (__bf16)1.0f;

    // Rv init = I (t=0: R = I), in sig-permuted C layout
    floatx4 Rv[4];
    #pragma unroll
    for (int jt = 0; jt < 4; ++jt)
        #pragma unroll
        for (int r = 0; r < 4; ++r) Rv[jt][r] = IS[sig(jt, 4*q + r)];

    // Compiler barrier: LDS reads above cannot be rematerialized in-loop.
    __asm__ volatile("" ::: "memory");

    const int b = 16*w + l;
    const float* xin = xg + b * (T_ * S_);
    float* outp = out + (size_t)b * T_ * U_ + u;

    const floatx4 z = {0.f, 0.f, 0.f, 0.f};
    floatx4 Ev[4], gv[4];
    float ll = 0.f, sp1 = 0.f, sp2 = 0.f, rsA = 1.0f;

    // Persistent E B-operand fragment: only k<4 (q==0) ever non-zero.
    bf16x8 be;
    #pragma unroll
    for (int p = 0; p < 8; ++p) be[p] = (__bf16)0.f;

    // ---------------- pipeline fill ----------------
    floatx4 x0 = *(const floatx4*)xin;
    floatx4 xA = *(const floatx4*)(xin + S_);       // x_1
    floatx4 xB = *(const floatx4*)(xin + 2 * S_);   // x_2

    {
        if (q == 0) {
            be[0] = (__bf16)x0.x; be[1] = (__bf16)x0.y;
            be[2] = (__bf16)x0.z; be[3] = (__bf16)x0.w;
        }
        #pragma unroll
        for (int jt = 0; jt < 4; ++jt)
            Ev[jt] = __builtin_amdgcn_mfma_f32_16x16x32_bf16(afragE[jt], be, z, 0, 0, 0);
    }

    // ---------------- t = 0 .. T-1 ----------------
    #pragma unroll 2
    for (int t = 0; t < T_; ++t) {
        // gv_t = Ev_t o Rv_t
        #pragma unroll
        for (int jt = 0; jt < 4; ++jt) gv[jt] = Ev[jt] * Rv[jt];

        // pack b_t = bf16(gv_t)  (scale carried inside Ev)
        bf16x8 bf0, bf1;
        #pragma unroll
        for (int p = 0; p < 4; ++p) {
            bf0[p]     = (__bf16)gv[0][p];
            bf0[4 + p] = (__bf16)gv[1][p];
            bf1[p]     = (__bf16)gv[2][p];
            bf1[4 + p] = (__bf16)gv[3][p];
        }

        // R_{t+1} = A^T b_t
        #pragma unroll
        for (int jt = 0; jt < 4; ++jt) {
            floatx4 acc = __builtin_amdgcn_mfma_f32_16x16x32_bf16(afrag[jt][0], bf0, z, 0, 0, 0);
            Rv[jt] = __builtin_amdgcn_mfma_f32_16x16x32_bf16(afrag[jt][1], bf1, acc, 0, 0, 0);
        }

        // ss_t via all-ones MFMA: every lane gets sum_j g[j][its own b].
        floatx4 sacc = __builtin_amdgcn_mfma_f32_16x16x32_bf16(onesA, bf0, z, 0, 0, 0);
        sacc = __builtin_amdgcn_mfma_f32_16x16x32_bf16(onesA, bf1, sacc, 0, 0, 0);
        float ss = sacc[0];
        float sg = __logf(ss);
        float rs = __builtin_amdgcn_rcpf(ss);

        // ll_t = ll_{t-1} + sigma_t - sigma_{t-1} + sigma_{t-2}
        ll += sg - sp1 + sp2;
        if (q == 0) outp[t * U_] = ll;
        sp2 = sp1; sp1 = sg;

        // Ev_{t+1}: x_{t+1} scaled by rs_{t-1} (rsA not yet updated)
        if (q == 0) {
            floatx4 xs = xA * rsA;
            be[0] = (__bf16)xs.x; be[1] = (__bf16)xs.y;
            be[2] = (__bf16)xs.z; be[3] = (__bf16)xs.w;
        }
        #pragma unroll
        for (int jt = 0; jt < 4; ++jt)
            Ev[jt] = __builtin_amdgcn_mfma_f32_16x16x32_bf16(afragE[jt], be, z, 0, 0, 0);
        rsA = rs;

        // x ring: 2 iterations of load slack
        xA = xB;
        int tp = (t + 3 < T_) ? t + 3 : T_ - 1;
        xB = *(const floatx4*)(xin + tp * S_);
    }
}

extern "C" void kernel_launch(void* const* d_in, const int* in_sizes, int n_in,
                              void* d_out, int out_size, void* d_ws, size_t ws_size,
                              hipStream_t stream) {
    const float* xg    = (const float*)d_in[0];
    const float* trans = (const float*)d_in[1];
    const float* emis  = (const float*)d_in[2];
    const float* initk = (const float*)d_in[3];
    float* out = (float*)d_out;
    hipLaunchKernelGGL(hmm_fwd_kernel, dim3(U_), dim3(256), 0, stream,
                       xg, trans, emis, initk, out);
}